// Round 8
// baseline (819.816 us; speedup 1.0000x reference)
//
#include <hip/hip_runtime.h>
#include <hip/hip_bf16.h>

typedef unsigned short b16;
typedef __attribute__((ext_vector_type(8))) unsigned short us8;
typedef __attribute__((ext_vector_type(8))) short short8;   // MFMA A/B frag (8 bf16)
typedef __attribute__((ext_vector_type(4))) float float4v;  // MFMA C/D frag

#define NN 100000
#define NE 600000

__device__ __forceinline__ float bf2f(b16 u) {
    return __uint_as_float(((unsigned)u) << 16);
}
__device__ __forceinline__ b16 f2bf(float f) {
    unsigned x = __float_as_uint(f);
    return (b16)((x + 0x7fffu + ((x >> 16) & 1u)) >> 16);
}

// ---------- dtype detection: flags[0]=1 if float tensors fp32, flags[1]=1 if idx int64
__global__ void k_detect(const void* __restrict__ y, const void* __restrict__ ei,
                         int* __restrict__ flags) {
    if (threadIdx.x == 0 && blockIdx.x == 0) {
        const b16* p = (const b16*)y;
        int f32 = 0;
        for (int i = 0; i < 128; ++i) {
            float v = bf2f(p[i]);
            if (!(fabsf(v) < 1e4f)) { f32 = 1; break; }
        }
        flags[0] = f32;
        const long long* q = (const long long*)ei;
        int i64 = 1;
        for (int i = 0; i < 4; ++i) {
            long long v = q[i];
            if (v < 0 || v >= NN) i64 = 0;
        }
        flags[1] = i64;
    }
}

__global__ void k_cvt(const void* __restrict__ in, float* __restrict__ out, int n,
                      const int* __restrict__ flags) {
    int i = blockIdx.x * blockDim.x + threadIdx.x;
    if (i >= n) return;
    out[i] = flags[0] ? ((const float*)in)[i] : bf2f(((const b16*)in)[i]);
}

// ---------- edge_index normalize ----------
__global__ void k_idx(const void* __restrict__ ei, int* __restrict__ src32,
                      int* __restrict__ dst32, const int* __restrict__ flags) {
    int e = blockIdx.x * blockDim.x + threadIdx.x;
    if (e >= NE) return;
    int s, d;
    if (flags[1]) {
        const long long* p = (const long long*)ei;
        s = (int)p[e];
        d = (int)p[NE + e];
    } else {
        const int* p = (const int*)ei;
        s = p[e];
        d = p[NE + e];
    }
    src32[e] = ((unsigned)s < NN) ? s : 0;
    dst32[e] = ((unsigned)d < NN) ? d : 0;
}

// ---------- degree (weighted) + CSR count ----------
__global__ void k_degcnt(const int* __restrict__ dst, const void* __restrict__ ea,
                         float* __restrict__ deg, int* __restrict__ cnt,
                         const int* __restrict__ flags) {
    int e = blockIdx.x * blockDim.x + threadIdx.x;
    if (e >= NE) return;
    float w = flags[0] ? ((const float*)ea)[e] : bf2f(((const b16*)ea)[e]);
    int d = dst[e];
    unsafeAtomicAdd(&deg[d], w);
    atomicAdd(&cnt[d], 1);
}

__global__ void k_dis(float* deg) {
    int n = blockIdx.x * blockDim.x + threadIdx.x;
    if (n < NN) {
        float d = deg[n];
        deg[n] = (d > 0.f) ? rsqrtf(fmaxf(d, 1e-12f)) : 0.f;
    }
}

// ---------- 3-phase exclusive scan of cnt[NN] -> rowptr[NN+1] ----------
#define SCAN_B 1024
#define SCAN_NB ((NN + SCAN_B - 1) / SCAN_B)

__global__ __launch_bounds__(SCAN_B) void k_scan1(const int* __restrict__ cnt,
                                                  int* __restrict__ inc,
                                                  int* __restrict__ bsum) {
    __shared__ int s[SCAN_B];
    int i = blockIdx.x * SCAN_B + threadIdx.x;
    s[threadIdx.x] = (i < NN) ? cnt[i] : 0;
    __syncthreads();
    for (int off = 1; off < SCAN_B; off <<= 1) {
        int t = (threadIdx.x >= off) ? s[threadIdx.x - off] : 0;
        __syncthreads();
        s[threadIdx.x] += t;
        __syncthreads();
    }
    if (i < NN) inc[i] = s[threadIdx.x];
    if (threadIdx.x == SCAN_B - 1) bsum[blockIdx.x] = s[SCAN_B - 1];
}

__global__ void k_scan2(int* bsum) {
    if (threadIdx.x == 0 && blockIdx.x == 0) {
        int a = 0;
        for (int i = 0; i < SCAN_NB; ++i) {
            int t = bsum[i];
            bsum[i] = a;
            a += t;
        }
    }
}

__global__ void k_scan3(const int* __restrict__ inc, const int* __restrict__ bsum,
                        int* __restrict__ rowptr) {
    int i = blockIdx.x * blockDim.x + threadIdx.x;
    if (i == 0) rowptr[0] = 0;
    if (i < NN) rowptr[i + 1] = inc[i] + bsum[i / SCAN_B];
}

// ---------- fill CSR ----------
__global__ void k_fill(const int* __restrict__ src, const int* __restrict__ dst,
                       const void* __restrict__ ea, const float* __restrict__ dis,
                       const int* __restrict__ rowptr, int* __restrict__ fill,
                       int* __restrict__ csrc, float* __restrict__ cw,
                       const int* __restrict__ flags) {
    int e = blockIdx.x * blockDim.x + threadIdx.x;
    if (e >= NE) return;
    float a = flags[0] ? ((const float*)ea)[e] : bf2f(((const b16*)ea)[e]);
    int d = dst[e];
    int s = src[e];
    int pos = rowptr[d] + atomicAdd(&fill[d], 1);
    csrc[pos] = s;
    cw[pos] = dis[s] * a * dis[d];
}

// ---------- pack W (fp32/bf16 [512][NC]) into B-fragment order ----------
__global__ void k_pack(const void* __restrict__ W, b16* __restrict__ Wp, int NC,
                       const int* __restrict__ flags) {
    int f = blockIdx.x * blockDim.x + threadIdx.x;
    int total = 512 * NC / 8;
    if (f >= total) return;
    int lane = f & 63;
    int rest = f >> 6;
    int CT = NC >> 4;
    int ct = rest % CT, ks = rest / CT;
    int k0 = 32 * ks + (lane >> 4) * 8;
    int col = 16 * ct + (lane & 15);
    us8 v;
#pragma unroll
    for (int j = 0; j < 8; ++j) {
        float x = flags[0] ? ((const float*)W)[(size_t)(k0 + j) * NC + col]
                           : bf2f(((const b16*)W)[(size_t)(k0 + j) * NC + col]);
        v[j] = f2bf(x);
    }
    *(us8*)&Wp[(size_t)f * 8] = v;
}

// ---------- initial cast y -> XC cols [0,128) (bf16, row stride 512) ----------
__global__ void k_cast(const void* __restrict__ y, b16* __restrict__ XC,
                       const int* __restrict__ flags) {
    int i = blockIdx.x * blockDim.x + threadIdx.x;
    if (i >= NN * 32) return;
    int row = i >> 5, cg = i & 31;
    float4 v;
    if (flags[0]) {
        v = ((const float4*)y)[i];
    } else {
        ushort4 u = ((const ushort4*)y)[i];
        v = make_float4(bf2f(u.x), bf2f(u.y), bf2f(u.z), bf2f(u.w));
    }
    ushort4 o;
    o.x = f2bf(v.x); o.y = f2bf(v.y); o.z = f2bf(v.z); o.w = f2bf(v.w);
    *(ushort4*)&XC[(size_t)row * 512 + 4 * cg] = o;
}

// ---------- SpMM gather: cols [ci,ci+128) -> [co,co+128) ----------
// wave = 1 node; each lane owns 2 adjacent cols (one dword of bf16x2).
// Per edge: 1 coalesced dword gather + 2 cvt + 2 fma. 4 edges in flight
// (predicated, OOB weight=0, index clamped); 2 independent accumulators;
// no cross-lane reduction.
__global__ __launch_bounds__(256) void k_spmm(b16* __restrict__ XC, int ci, int co,
                                              const int* __restrict__ rowptr,
                                              const int* __restrict__ csrc,
                                              const float* __restrict__ cw) {
    int gid = blockIdx.x * blockDim.x + threadIdx.x;
    int node = gid >> 6;
    if (node >= NN) return;
    int lane = gid & 63;
    int beg = rowptr[node], end = rowptr[node + 1];
    int coff = ci + 2 * lane;

    float ax0 = 0.f, ay0 = 0.f, ax1 = 0.f, ay1 = 0.f;
    for (int i = beg; i < end; i += 4) {
        int lim = end - 1;
        int e1 = i + 1, e2 = i + 2, e3 = i + 3;
        float w0 = cw[i];
        float w1 = (e1 < end) ? cw[e1] : 0.f;
        float w2 = (e2 < end) ? cw[e2] : 0.f;
        float w3 = (e3 < end) ? cw[e3] : 0.f;
        int s0 = csrc[i];
        int s1 = csrc[e1 < lim ? e1 : lim];
        int s2 = csrc[e2 < lim ? e2 : lim];
        int s3 = csrc[e3 < lim ? e3 : lim];
        unsigned u0 = *(const unsigned*)&XC[(size_t)s0 * 512 + coff];
        unsigned u1 = *(const unsigned*)&XC[(size_t)s1 * 512 + coff];
        unsigned u2 = *(const unsigned*)&XC[(size_t)s2 * 512 + coff];
        unsigned u3 = *(const unsigned*)&XC[(size_t)s3 * 512 + coff];
        ax0 = fmaf(w0, __uint_as_float(u0 << 16), ax0);
        ay0 = fmaf(w0, __uint_as_float(u0 & 0xFFFF0000u), ay0);
        ax1 = fmaf(w1, __uint_as_float(u1 << 16), ax1);
        ay1 = fmaf(w1, __uint_as_float(u1 & 0xFFFF0000u), ay1);
        ax0 = fmaf(w2, __uint_as_float(u2 << 16), ax0);
        ay0 = fmaf(w2, __uint_as_float(u2 & 0xFFFF0000u), ay0);
        ax1 = fmaf(w3, __uint_as_float(u3 << 16), ax1);
        ay1 = fmaf(w3, __uint_as_float(u3 & 0xFFFF0000u), ay1);
    }
    ax0 += ax1;
    ay0 += ay1;
    ushort2 o;
    o.x = f2bf(ax0);
    o.y = f2bf(ay0);
    *(ushort2*)&XC[(size_t)node * 512 + co + 2 * lane] = o;
}

// ---------- MFMA GEMM + fused BN-stat epilogue ----------
// OUT[NN x NC](bf16) = XC[NN x 512](bf16) @ Wp (+bias); col sums/sumsq -> gsum/gsq.
// Wave owns 64 rows (4 row-tiles) x 64 cols (4 col-tiles); block = 4 waves =
// 256 rows x 64 cols; grid = (391, NC/64). No LDS staging: A frags (16B
// contiguous, HBM stream) + packed-B frags (L2-hot) loaded straight to regs,
// ping-pong buffers (full unroll -> no copies), A issued before B each step.
template <int CTF>  // frags per k-step in Wp: 8 (NC=128) or 4 (NC=64)
__global__ __launch_bounds__(256) void k_mgemm(const b16* __restrict__ XC,
                                               const b16* __restrict__ Wp,
                                               const float* __restrict__ bias,
                                               b16* __restrict__ OUT,
                                               float* __restrict__ gsum,
                                               float* __restrict__ gsq) {
    constexpr int NC = CTF * 16;
    __shared__ float csum[64], csq[64];
    const int tid = threadIdx.x;
    const int wave = tid >> 6;
    const int lane = tid & 63;
    const int quad = lane >> 4;
    const int l15 = lane & 15;
    const int cb = blockIdx.y;          // 64-col block
    const int cbase = cb * 4;           // frag offset within a k-step
    const int rbase = blockIdx.x * 256 + wave * 64;

    for (int i = tid; i < 64; i += 256) {
        csum[i] = 0.f;
        csq[i] = 0.f;
    }

    float4v acc[4][4];
#pragma unroll
    for (int rt = 0; rt < 4; ++rt)
#pragma unroll
        for (int ct = 0; ct < 4; ++ct) acc[rt][ct] = (float4v)(0.f);

    const b16* gA[4];
#pragma unroll
    for (int rt = 0; rt < 4; ++rt) {
        int r = rbase + 16 * rt + l15;
        if (r >= NN) r = NN - 1;  // clamp; dead rows excluded from store/stats
        gA[rt] = XC + (size_t)r * 512 + quad * 8;
    }
    const b16* gB = Wp + (size_t)cbase * 512 + lane * 8;

    short8 ab[2][4], bb[2][4];
#pragma unroll
    for (int rt = 0; rt < 4; ++rt) ab[0][rt] = *(const short8*)(gA[rt]);
#pragma unroll
    for (int ct = 0; ct < 4; ++ct) bb[0][ct] = *(const short8*)(gB + ct * 512);

#pragma unroll
    for (int ks = 0; ks < 16; ++ks) {
        const int cur = ks & 1, nxt = cur ^ 1;
        if (ks < 15) {
#pragma unroll
            for (int rt = 0; rt < 4; ++rt)
                ab[nxt][rt] = *(const short8*)(gA[rt] + 32 * (ks + 1));
#pragma unroll
            for (int ct = 0; ct < 4; ++ct)
                bb[nxt][ct] = *(const short8*)(gB + (size_t)(ks + 1) * CTF * 512 + ct * 512);
        }
#pragma unroll
        for (int rt = 0; rt < 4; ++rt)
#pragma unroll
            for (int ct = 0; ct < 4; ++ct)
                acc[rt][ct] = __builtin_amdgcn_mfma_f32_16x16x32_bf16(
                    ab[cur][rt], bb[cur][ct], acc[rt][ct], 0, 0, 0);
    }

    // epilogue: bf16 store + BN stats (C/D: col=lane&15, row=quad*4+reg)
#pragma unroll
    for (int rt = 0; rt < 4; ++rt) {
#pragma unroll
        for (int ct = 0; ct < 4; ++ct) {
            int cl = 16 * ct + l15;          // col within 64-col block
            int col = cb * 64 + cl;          // global col
            float bv = bias ? bias[col] : 0.f;
            float s = 0.f, sq = 0.f;
#pragma unroll
            for (int r = 0; r < 4; ++r) {
                int row = rbase + 16 * rt + quad * 4 + r;
                if (row < NN) {
                    float v = acc[rt][ct][r] + bv;
                    OUT[(size_t)row * NC + col] = f2bf(v);
                    s += v;
                    sq += v * v;
                }
            }
            s += __shfl_xor(s, 16);
            s += __shfl_xor(s, 32);
            sq += __shfl_xor(sq, 16);
            sq += __shfl_xor(sq, 32);
            if (quad == 0) {
                atomicAdd(&csum[cl], s);
                atomicAdd(&csq[cl], sq);
            }
        }
    }
    __syncthreads();
    if (tid < 64) {
        unsafeAtomicAdd(&gsum[cb * 64 + tid], csum[tid]);
        unsafeAtomicAdd(&gsq[cb * 64 + tid], csq[tid]);
    }
}

// ---------- BatchNorm params ----------
__global__ void k_bnparam(const float* gsum, const float* gsq, const float* g,
                          const float* be, float* scale, float* shift, int ncols) {
    int c = threadIdx.x;
    if (c < ncols) {
        float m = gsum[c] * (1.f / NN);
        float v = gsq[c] * (1.f / NN) - m * m;
        v = fmaxf(v, 0.f);
        float s = rsqrtf(v + 1e-5f) * g[c];
        scale[c] = s;
        shift[c] = be[c] - m * s;
    }
}

// layers 1,2: write bf16 into XC cols [0,128)
__global__ void k_bnapply_mid(const b16* __restrict__ OUT,
                              const float* __restrict__ scale,
                              const float* __restrict__ shift, b16* __restrict__ XC) {
    int i = blockIdx.x * blockDim.x + threadIdx.x;
    if (i >= NN * 64) return;
    int row = i >> 6, c = (i & 63) * 2;
    ushort2 u = *(const ushort2*)&OUT[(size_t)row * 128 + c];
    float a = fmaf(bf2f(u.x), scale[c], shift[c]);
    float b = fmaf(bf2f(u.y), scale[c + 1], shift[c + 1]);
    a = a > 0.f ? a : 0.01f * a;
    b = b > 0.f ? b : 0.01f * b;
    ushort2 o;
    o.x = f2bf(a);
    o.y = f2bf(b);
    *(ushort2*)&XC[(size_t)row * 512 + c] = o;
}

// layer 3: write d_out (fp32 or bf16 per flag), NC=64
__global__ void k_bnapply_last(const b16* __restrict__ OUT,
                               const float* __restrict__ scale,
                               const float* __restrict__ shift, void* __restrict__ dout,
                               const int* __restrict__ flags) {
    int i = blockIdx.x * blockDim.x + threadIdx.x;
    if (i >= NN * 64) return;
    int c = i & 63;
    float v = fmaf(bf2f(OUT[i]), scale[c], shift[c]);
    v = v > 0.f ? v : 0.01f * v;
    if (flags[0])
        ((float*)dout)[i] = v;
    else
        ((b16*)dout)[i] = f2bf(v);
}

// ---------- driver ----------
#define PB_B1 0
#define PB_B2 128
#define PB_G1 256
#define PB_BE1 384
#define PB_G2 512
#define PB_BE2 640
#define PB_G3 768
#define PB_BE3 832
#define PB_SZ 896

extern "C" void kernel_launch(void* const* d_in, const int* in_sizes, int n_in,
                              void* d_out, int out_size, void* d_ws, size_t ws_size,
                              hipStream_t stream) {
    const void* y   = d_in[0];
    const void* ei  = d_in[1];
    const void* ea  = d_in[2];
    const void* W1  = d_in[3];
    const void* b1  = d_in[4];
    const void* g1  = d_in[5];
    const void* be1 = d_in[6];
    const void* W2  = d_in[7];
    const void* b2  = d_in[8];
    const void* g2  = d_in[9];
    const void* be2 = d_in[10];
    const void* W3  = d_in[11];
    const void* g3  = d_in[12];
    const void* be3 = d_in[13];

    char* w = (char*)d_ws;
    size_t used = 0;
    auto carve = [&](size_t bytes) -> char* {
        char* p = w + used;
        used += (bytes + 255) & ~(size_t)255;
        return p;
    };

    int* flags   = (int*)carve(16);
    int* src32   = (int*)carve((size_t)NE * 4);
    int* dst32   = (int*)carve((size_t)NE * 4);
    float* deg   = (float*)carve((size_t)NN * 4);
    int* cnt     = (int*)carve((size_t)NN * 4);
    int* rowptr  = (int*)carve((size_t)(NN + 1) * 4);
    int* cscan   = (int*)carve((size_t)NN * 4);
    int* bsum    = (int*)carve((size_t)SCAN_NB * 4);
    int* csrc    = (int*)carve((size_t)NE * 4);
    float* cw    = (float*)carve((size_t)NE * 4);
    float* PB    = (float*)carve(PB_SZ * 4);
    b16* Wp1     = (b16*)carve((size_t)512 * 128 * 2);
    b16* Wp2     = (b16*)carve((size_t)512 * 128 * 2);
    b16* Wp3     = (b16*)carve((size_t)512 * 64 * 2);
    b16* OUT     = (b16*)carve((size_t)NN * 128 * 2);
    float* gsum  = (float*)carve(128 * 4);
    float* gsq   = (float*)carve(128 * 4);
    float* scale = (float*)carve(128 * 4);
    float* shift = (float*)carve(128 * 4);
    b16* XC      = (b16*)carve((size_t)NN * 512 * 2);

    // ----- detection + param normalize + weight pack -----
    k_detect<<<1, 64, 0, stream>>>(y, ei, flags);
    auto cvt = [&](const void* in, float* out, int n) {
        k_cvt<<<(n + 127) / 128, 128, 0, stream>>>(in, out, n, flags);
    };
    cvt(b1, PB + PB_B1, 128);
    cvt(b2, PB + PB_B2, 128);
    cvt(g1, PB + PB_G1, 128);
    cvt(be1, PB + PB_BE1, 128);
    cvt(g2, PB + PB_G2, 128);
    cvt(be2, PB + PB_BE2, 128);
    cvt(g3, PB + PB_G3, 64);
    cvt(be3, PB + PB_BE3, 64);
    k_pack<<<(512 * 128 / 8 + 255) / 256, 256, 0, stream>>>(W1, Wp1, 128, flags);
    k_pack<<<(512 * 128 / 8 + 255) / 256, 256, 0, stream>>>(W2, Wp2, 128, flags);
    k_pack<<<(512 * 64 / 8 + 255) / 256, 256, 0, stream>>>(W3, Wp3, 64, flags);

    // ----- graph prep -----
    k_idx<<<(NE + 255) / 256, 256, 0, stream>>>(ei, src32, dst32, flags);
    hipMemsetAsync(deg, 0, (size_t)NN * 4, stream);
    hipMemsetAsync(cnt, 0, (size_t)NN * 4, stream);
    k_degcnt<<<(NE + 255) / 256, 256, 0, stream>>>(dst32, ea, deg, cnt, flags);
    k_dis<<<(NN + 255) / 256, 256, 0, stream>>>(deg);
    k_scan1<<<SCAN_NB, SCAN_B, 0, stream>>>(cnt, cscan, bsum);
    k_scan2<<<1, 64, 0, stream>>>(bsum);
    k_scan3<<<(NN + 255) / 256, 256, 0, stream>>>(cscan, bsum, rowptr);
    hipMemsetAsync(cnt, 0, (size_t)NN * 4, stream);
    k_fill<<<(NE + 255) / 256, 256, 0, stream>>>(src32, dst32, ea, deg, rowptr, cnt,
                                                 csrc, cw, flags);

    // ----- layers -----
    k_cast<<<(NN * 32 + 255) / 256, 256, 0, stream>>>(y, XC, flags);

    auto spmm = [&](int ci, int co) {
        k_spmm<<<(NN * 64 + 255) / 256, 256, 0, stream>>>(XC, ci, co, rowptr, csrc, cw);
    };
    const int gemm_gx = (NN + 255) / 256;

    auto layer = [&](const b16* Wp, const float* bias, const float* g, const float* be,
                     int NC, bool last) {
        spmm(0, 128);
        spmm(128, 256);
        spmm(256, 384);
        hipMemsetAsync(gsum, 0, NC * 4, stream);
        hipMemsetAsync(gsq, 0, NC * 4, stream);
        if (NC == 128)
            k_mgemm<8><<<dim3(gemm_gx, 2), 256, 0, stream>>>(XC, Wp, bias, OUT, gsum, gsq);
        else
            k_mgemm<4><<<dim3(gemm_gx, 1), 256, 0, stream>>>(XC, Wp, bias, OUT, gsum, gsq);
        k_bnparam<<<1, NC, 0, stream>>>(gsum, gsq, g, be, scale, shift, NC);
        if (last)
            k_bnapply_last<<<(NN * 64 + 255) / 256, 256, 0, stream>>>(OUT, scale, shift,
                                                                      d_out, flags);
        else
            k_bnapply_mid<<<(NN * 64 + 255) / 256, 256, 0, stream>>>(OUT, scale, shift,
                                                                     XC);
    };

    layer(Wp1, PB + PB_B1, PB + PB_G1, PB + PB_BE1, 128, false);
    layer(Wp2, PB + PB_B2, PB + PB_G2, PB + PB_BE2, 128, false);
    layer(Wp3, nullptr, PB + PB_G3, PB + PB_BE3, 64, true);
}

// Round 9
// 802.746 us; speedup vs baseline: 1.0213x; 1.0213x over previous
//
#include <hip/hip_runtime.h>
#include <hip/hip_bf16.h>

typedef unsigned short b16;
typedef __attribute__((ext_vector_type(8))) unsigned short us8;
typedef __attribute__((ext_vector_type(8))) short short8;   // MFMA A/B frag (8 bf16)
typedef __attribute__((ext_vector_type(4))) float float4v;  // MFMA C/D frag

#define NN 100000
#define NE 600000
#define INV_NN (1.0f / NN)

__device__ __forceinline__ float bf2f(b16 u) {
    return __uint_as_float(((unsigned)u) << 16);
}
__device__ __forceinline__ b16 f2bf(float f) {
    unsigned x = __float_as_uint(f);
    return (b16)((x + 0x7fffu + ((x >> 16) & 1u)) >> 16);
}

// ---------- dtype detection: flags[0]=1 if float tensors fp32, flags[1]=1 if idx int64
__global__ void k_detect(const void* __restrict__ y, const void* __restrict__ ei,
                         int* __restrict__ flags) {
    if (threadIdx.x == 0 && blockIdx.x == 0) {
        const b16* p = (const b16*)y;
        int f32 = 0;
        for (int i = 0; i < 128; ++i) {
            float v = bf2f(p[i]);
            if (!(fabsf(v) < 1e4f)) { f32 = 1; break; }
        }
        flags[0] = f32;
        const long long* q = (const long long*)ei;
        int i64 = 1;
        for (int i = 0; i < 4; ++i) {
            long long v = q[i];
            if (v < 0 || v >= NN) i64 = 0;
        }
        flags[1] = i64;
    }
}

// ---------- all small param vectors -> fp32 param block (one launch) ----------
__global__ void k_cvt_all(const void* b1, const void* b2, const void* g1,
                          const void* be1, const void* g2, const void* be2,
                          const void* g3, const void* be3, float* __restrict__ PB,
                          const int* __restrict__ flags) {
    int i = threadIdx.x;  // 896 threads
    const void* src;
    int off;
    if (i < 128) { src = b1; off = i; }
    else if (i < 256) { src = b2; off = i - 128; }
    else if (i < 384) { src = g1; off = i - 256; }
    else if (i < 512) { src = be1; off = i - 384; }
    else if (i < 640) { src = g2; off = i - 512; }
    else if (i < 768) { src = be2; off = i - 640; }
    else if (i < 832) { src = g3; off = i - 768; }
    else { src = be3; off = i - 832; }
    PB[i] = flags[0] ? ((const float*)src)[off] : bf2f(((const b16*)src)[off]);
}

// ---------- edge_index normalize ----------
__global__ void k_idx(const void* __restrict__ ei, int* __restrict__ src32,
                      int* __restrict__ dst32, const int* __restrict__ flags) {
    int e = blockIdx.x * blockDim.x + threadIdx.x;
    if (e >= NE) return;
    int s, d;
    if (flags[1]) {
        const long long* p = (const long long*)ei;
        s = (int)p[e];
        d = (int)p[NE + e];
    } else {
        const int* p = (const int*)ei;
        s = p[e];
        d = p[NE + e];
    }
    src32[e] = ((unsigned)s < NN) ? s : 0;
    dst32[e] = ((unsigned)d < NN) ? d : 0;
}

// ---------- degree (weighted) + CSR count ----------
__global__ void k_degcnt(const int* __restrict__ dst, const void* __restrict__ ea,
                         float* __restrict__ deg, int* __restrict__ cnt,
                         const int* __restrict__ flags) {
    int e = blockIdx.x * blockDim.x + threadIdx.x;
    if (e >= NE) return;
    float w = flags[0] ? ((const float*)ea)[e] : bf2f(((const b16*)ea)[e]);
    int d = dst[e];
    unsafeAtomicAdd(&deg[d], w);
    atomicAdd(&cnt[d], 1);
}

__global__ void k_dis(float* deg) {
    int n = blockIdx.x * blockDim.x + threadIdx.x;
    if (n < NN) {
        float d = deg[n];
        deg[n] = (d > 0.f) ? rsqrtf(fmaxf(d, 1e-12f)) : 0.f;
    }
}

// ---------- 3-phase exclusive scan of cnt[NN] -> rowptr[NN+1] ----------
#define SCAN_B 1024
#define SCAN_NB ((NN + SCAN_B - 1) / SCAN_B)

__global__ __launch_bounds__(SCAN_B) void k_scan1(const int* __restrict__ cnt,
                                                  int* __restrict__ inc,
                                                  int* __restrict__ bsum) {
    __shared__ int s[SCAN_B];
    int i = blockIdx.x * SCAN_B + threadIdx.x;
    s[threadIdx.x] = (i < NN) ? cnt[i] : 0;
    __syncthreads();
    for (int off = 1; off < SCAN_B; off <<= 1) {
        int t = (threadIdx.x >= off) ? s[threadIdx.x - off] : 0;
        __syncthreads();
        s[threadIdx.x] += t;
        __syncthreads();
    }
    if (i < NN) inc[i] = s[threadIdx.x];
    if (threadIdx.x == SCAN_B - 1) bsum[blockIdx.x] = s[SCAN_B - 1];
}

__global__ void k_scan2(int* bsum) {
    if (threadIdx.x == 0 && blockIdx.x == 0) {
        int a = 0;
        for (int i = 0; i < SCAN_NB; ++i) {
            int t = bsum[i];
            bsum[i] = a;
            a += t;
        }
    }
}

__global__ void k_scan3(const int* __restrict__ inc, const int* __restrict__ bsum,
                        int* __restrict__ rowptr) {
    int i = blockIdx.x * blockDim.x + threadIdx.x;
    if (i == 0) rowptr[0] = 0;
    if (i < NN) rowptr[i + 1] = inc[i] + bsum[i / SCAN_B];
}

// ---------- fill CSR ----------
__global__ void k_fill(const int* __restrict__ src, const int* __restrict__ dst,
                       const void* __restrict__ ea, const float* __restrict__ dis,
                       const int* __restrict__ rowptr, int* __restrict__ fill,
                       int* __restrict__ csrc, float* __restrict__ cw,
                       const int* __restrict__ flags) {
    int e = blockIdx.x * blockDim.x + threadIdx.x;
    if (e >= NE) return;
    float a = flags[0] ? ((const float*)ea)[e] : bf2f(((const b16*)ea)[e]);
    int d = dst[e];
    int s = src[e];
    int pos = rowptr[d] + atomicAdd(&fill[d], 1);
    csrc[pos] = s;
    cw[pos] = dis[s] * a * dis[d];
}

// ---------- pack W (fp32/bf16 [512][NC]) into B-fragment order ----------
__global__ void k_pack(const void* __restrict__ W, b16* __restrict__ Wp, int NC,
                       const int* __restrict__ flags) {
    int f = blockIdx.x * blockDim.x + threadIdx.x;
    int total = 512 * NC / 8;
    if (f >= total) return;
    int lane = f & 63;
    int rest = f >> 6;
    int CT = NC >> 4;
    int ct = rest % CT, ks = rest / CT;
    int k0 = 32 * ks + (lane >> 4) * 8;
    int col = 16 * ct + (lane & 15);
    us8 v;
#pragma unroll
    for (int j = 0; j < 8; ++j) {
        float x = flags[0] ? ((const float*)W)[(size_t)(k0 + j) * NC + col]
                           : bf2f(((const b16*)W)[(size_t)(k0 + j) * NC + col]);
        v[j] = f2bf(x);
    }
    *(us8*)&Wp[(size_t)f * 8] = v;
}

// ---------- initial cast y -> XC cols [0,128) (bf16, row stride 512) ----------
__global__ void k_cast(const void* __restrict__ y, b16* __restrict__ XC,
                       const int* __restrict__ flags) {
    int i = blockIdx.x * blockDim.x + threadIdx.x;
    if (i >= NN * 32) return;
    int row = i >> 5, cg = i & 31;
    float4 v;
    if (flags[0]) {
        v = ((const float4*)y)[i];
    } else {
        ushort4 u = ((const ushort4*)y)[i];
        v = make_float4(bf2f(u.x), bf2f(u.y), bf2f(u.z), bf2f(u.w));
    }
    ushort4 o;
    o.x = f2bf(v.x); o.y = f2bf(v.y); o.z = f2bf(v.z); o.w = f2bf(v.w);
    *(ushort4*)&XC[(size_t)row * 512 + 4 * cg] = o;
}

// ---------- plain SpMM gather: XC cols [ci,ci+128) -> [co,co+128) ----------
// wave = 1 node; lane owns 2 adjacent cols (dword of bf16x2); 4 edges in
// flight (predicated); 2 independent accumulators; no cross-lane reduce.
__global__ __launch_bounds__(256) void k_spmm(b16* __restrict__ XC, int ci, int co,
                                              const int* __restrict__ rowptr,
                                              const int* __restrict__ csrc,
                                              const float* __restrict__ cw) {
    int gid = blockIdx.x * blockDim.x + threadIdx.x;
    int node = gid >> 6;
    if (node >= NN) return;
    int lane = gid & 63;
    int beg = rowptr[node], end = rowptr[node + 1];
    int coff = ci + 2 * lane;

    float ax0 = 0.f, ay0 = 0.f, ax1 = 0.f, ay1 = 0.f;
    for (int i = beg; i < end; i += 4) {
        int lim = end - 1;
        int e1 = i + 1, e2 = i + 2, e3 = i + 3;
        float w0 = cw[i];
        float w1 = (e1 < end) ? cw[e1] : 0.f;
        float w2 = (e2 < end) ? cw[e2] : 0.f;
        float w3 = (e3 < end) ? cw[e3] : 0.f;
        int s0 = csrc[i];
        int s1 = csrc[e1 < lim ? e1 : lim];
        int s2 = csrc[e2 < lim ? e2 : lim];
        int s3 = csrc[e3 < lim ? e3 : lim];
        unsigned u0 = *(const unsigned*)&XC[(size_t)s0 * 512 + coff];
        unsigned u1 = *(const unsigned*)&XC[(size_t)s1 * 512 + coff];
        unsigned u2 = *(const unsigned*)&XC[(size_t)s2 * 512 + coff];
        unsigned u3 = *(const unsigned*)&XC[(size_t)s3 * 512 + coff];
        ax0 = fmaf(w0, __uint_as_float(u0 << 16), ax0);
        ay0 = fmaf(w0, __uint_as_float(u0 & 0xFFFF0000u), ay0);
        ax1 = fmaf(w1, __uint_as_float(u1 << 16), ax1);
        ay1 = fmaf(w1, __uint_as_float(u1 & 0xFFFF0000u), ay1);
        ax0 = fmaf(w2, __uint_as_float(u2 << 16), ax0);
        ay0 = fmaf(w2, __uint_as_float(u2 & 0xFFFF0000u), ay0);
        ax1 = fmaf(w3, __uint_as_float(u3 << 16), ax1);
        ay1 = fmaf(w3, __uint_as_float(u3 & 0xFFFF0000u), ay1);
    }
    ax0 += ax1;
    ay0 += ay1;
    ushort2 o;
    o.x = f2bf(ax0);
    o.y = f2bf(ay0);
    *(ushort2*)&XC[(size_t)node * 512 + co + 2 * lane] = o;
}

// ---------- fused BN+LReLU SpMM (first hop of layers 2,3) ----------
// X = lrelu(bn(OUT)); writes X into XC cols [0,128) (one row per node) and
// hop1 = A·X into XC cols [co,co+128). BN params computed in-wave from
// gsum/gsq + gamma/beta — no separate bnparam/bnapply pass.
__global__ __launch_bounds__(256) void k_spmm_bn(b16* __restrict__ XC,
                                                 const b16* __restrict__ OUT, int co,
                                                 const int* __restrict__ rowptr,
                                                 const int* __restrict__ csrc,
                                                 const float* __restrict__ cw,
                                                 const float* __restrict__ gsum,
                                                 const float* __restrict__ gsq,
                                                 const float* __restrict__ gamma,
                                                 const float* __restrict__ beta) {
    int gid = blockIdx.x * blockDim.x + threadIdx.x;
    int node = gid >> 6;
    if (node >= NN) return;
    int lane = gid & 63;
    int c = 2 * lane;
    // per-lane BN params for its 2 cols
    float m0 = gsum[c] * INV_NN, m1 = gsum[c + 1] * INV_NN;
    float v0 = fmaxf(gsq[c] * INV_NN - m0 * m0, 0.f);
    float v1 = fmaxf(gsq[c + 1] * INV_NN - m1 * m1, 0.f);
    float sc0 = rsqrtf(v0 + 1e-5f) * gamma[c];
    float sc1 = rsqrtf(v1 + 1e-5f) * gamma[c + 1];
    float sh0 = beta[c] - m0 * sc0;
    float sh1 = beta[c + 1] - m1 * sc1;

    int beg = rowptr[node], end = rowptr[node + 1];
    float ax0 = 0.f, ay0 = 0.f, ax1 = 0.f, ay1 = 0.f;
    for (int i = beg; i < end; i += 4) {
        int lim = end - 1;
        int e1 = i + 1, e2 = i + 2, e3 = i + 3;
        float w0 = cw[i];
        float w1 = (e1 < end) ? cw[e1] : 0.f;
        float w2 = (e2 < end) ? cw[e2] : 0.f;
        float w3 = (e3 < end) ? cw[e3] : 0.f;
        int s0 = csrc[i];
        int s1 = csrc[e1 < lim ? e1 : lim];
        int s2 = csrc[e2 < lim ? e2 : lim];
        int s3 = csrc[e3 < lim ? e3 : lim];
        unsigned u0 = *(const unsigned*)&OUT[(size_t)s0 * 128 + c];
        unsigned u1 = *(const unsigned*)&OUT[(size_t)s1 * 128 + c];
        unsigned u2 = *(const unsigned*)&OUT[(size_t)s2 * 128 + c];
        unsigned u3 = *(const unsigned*)&OUT[(size_t)s3 * 128 + c];
#define BNX(u) ({ float t = fmaf(__uint_as_float((u) << 16), sc0, sh0); t > 0.f ? t : 0.01f * t; })
#define BNY(u) ({ float t = fmaf(__uint_as_float((u) & 0xFFFF0000u), sc1, sh1); t > 0.f ? t : 0.01f * t; })
        ax0 = fmaf(w0, BNX(u0), ax0);
        ay0 = fmaf(w0, BNY(u0), ay0);
        ax1 = fmaf(w1, BNX(u1), ax1);
        ay1 = fmaf(w1, BNY(u1), ay1);
        ax0 = fmaf(w2, BNX(u2), ax0);
        ay0 = fmaf(w2, BNY(u2), ay0);
        ax1 = fmaf(w3, BNX(u3), ax1);
        ay1 = fmaf(w3, BNY(u3), ay1);
    }
    // per-node X-write: X[node] = lrelu(bn(OUT[node]))
    unsigned un = *(const unsigned*)&OUT[(size_t)node * 128 + c];
    float xn0 = BNX(un), xn1 = BNY(un);
#undef BNX
#undef BNY
    ushort2 ox;
    ox.x = f2bf(xn0);
    ox.y = f2bf(xn1);
    *(ushort2*)&XC[(size_t)node * 512 + c] = ox;

    ax0 += ax1;
    ay0 += ay1;
    ushort2 o;
    o.x = f2bf(ax0);
    o.y = f2bf(ay0);
    *(ushort2*)&XC[(size_t)node * 512 + co + 2 * lane] = o;
}

// ---------- MFMA GEMM + fused BN-stat epilogue ----------
// OUT[NN x NC](bf16) = XC[NN x 512](bf16) @ Wp (+bias); col sums/sumsq ->
// gsum/gsq. Wave owns 32 rows (2 row-tiles) x all NC cols; block = 4 waves =
// 128 rows; single col pass (A read once). No LDS staging; ping-pong regs.
template <int CT>
__global__ __launch_bounds__(256) void k_mgemm(const b16* __restrict__ XC,
                                               const b16* __restrict__ Wp,
                                               const float* __restrict__ bias,
                                               b16* __restrict__ OUT,
                                               float* __restrict__ gsum,
                                               float* __restrict__ gsq) {
    constexpr int NC = CT * 16;
    __shared__ float csum[NC], csq[NC];
    const int tid = threadIdx.x;
    const int wave = tid >> 6;
    const int lane = tid & 63;
    const int quad = lane >> 4;
    const int l15 = lane & 15;
    const int rbase = blockIdx.x * 128 + wave * 32;

    for (int i = tid; i < NC; i += 256) {
        csum[i] = 0.f;
        csq[i] = 0.f;
    }

    float4v acc[2][CT];
#pragma unroll
    for (int rt = 0; rt < 2; ++rt)
#pragma unroll
        for (int ct = 0; ct < CT; ++ct) acc[rt][ct] = (float4v)(0.f);

    const b16* gA[2];
#pragma unroll
    for (int rt = 0; rt < 2; ++rt) {
        int r = rbase + 16 * rt + l15;
        if (r >= NN) r = NN - 1;  // clamp; dead rows excluded from store/stats
        gA[rt] = XC + (size_t)r * 512 + quad * 8;
    }
    const b16* gB = Wp + lane * 8;

    short8 ab[2][2], bb[2][CT];
#pragma unroll
    for (int rt = 0; rt < 2; ++rt) ab[0][rt] = *(const short8*)(gA[rt]);
#pragma unroll
    for (int ct = 0; ct < CT; ++ct) bb[0][ct] = *(const short8*)(gB + ct * 512);

#pragma unroll
    for (int ks = 0; ks < 16; ++ks) {
        const int cur = ks & 1, nxt = cur ^ 1;
        if (ks < 15) {
#pragma unroll
            for (int rt = 0; rt < 2; ++rt)
                ab[nxt][rt] = *(const short8*)(gA[rt] + 32 * (ks + 1));
#pragma unroll
            for (int ct = 0; ct < CT; ++ct)
                bb[nxt][ct] =
                    *(const short8*)(gB + (size_t)(ks + 1) * CT * 512 + ct * 512);
        }
#pragma unroll
        for (int rt = 0; rt < 2; ++rt)
#pragma unroll
            for (int ct = 0; ct < CT; ++ct)
                acc[rt][ct] = __builtin_amdgcn_mfma_f32_16x16x32_bf16(
                    ab[cur][rt], bb[cur][ct], acc[rt][ct], 0, 0, 0);
    }

    // epilogue: bf16 store + BN stats (C/D: col=lane&15, row=quad*4+reg)
#pragma unroll
    for (int rt = 0; rt < 2; ++rt) {
#pragma unroll
        for (int ct = 0; ct < CT; ++ct) {
            int col = 16 * ct + l15;
            float bv = bias ? bias[col] : 0.f;
            float s = 0.f, sq = 0.f;
#pragma unroll
            for (int r = 0; r < 4; ++r) {
                int row = rbase + 16 * rt + quad * 4 + r;
                if (row < NN) {
                    float v = acc[rt][ct][r] + bv;
                    OUT[(size_t)row * NC + col] = f2bf(v);
                    s += v;
                    sq += v * v;
                }
            }
            s += __shfl_xor(s, 16);
            s += __shfl_xor(s, 32);
            sq += __shfl_xor(sq, 16);
            sq += __shfl_xor(sq, 32);
            if (quad == 0) {
                atomicAdd(&csum[col], s);
                atomicAdd(&csq[col], sq);
            }
        }
    }
    __syncthreads();
    for (int i = tid; i < NC; i += 256) {
        unsafeAtomicAdd(&gsum[i], csum[i]);
        unsafeAtomicAdd(&gsq[i], csq[i]);
    }
}

// ---------- layer-3 epilogue: BN params in-block, write d_out (NC=64) ----------
__global__ void k_bnlast(const b16* __restrict__ OUT, const float* __restrict__ gsum,
                         const float* __restrict__ gsq, const float* __restrict__ gamma,
                         const float* __restrict__ beta, void* __restrict__ dout,
                         const int* __restrict__ flags) {
    __shared__ float sc[64], sh[64];
    int tid = threadIdx.x;
    if (tid < 64) {
        float m = gsum[tid] * INV_NN;
        float v = fmaxf(gsq[tid] * INV_NN - m * m, 0.f);
        float s = rsqrtf(v + 1e-5f) * gamma[tid];
        sc[tid] = s;
        sh[tid] = beta[tid] - m * s;
    }
    __syncthreads();
    int i = blockIdx.x * blockDim.x + tid;
    if (i >= NN * 64) return;
    int c = i & 63;
    float v = fmaf(bf2f(OUT[i]), sc[c], sh[c]);
    v = v > 0.f ? v : 0.01f * v;
    if (flags[0])
        ((float*)dout)[i] = v;
    else
        ((b16*)dout)[i] = f2bf(v);
}

// ---------- driver ----------
#define PB_B1 0
#define PB_B2 128
#define PB_G1 256
#define PB_BE1 384
#define PB_G2 512
#define PB_BE2 640
#define PB_G3 768
#define PB_BE3 832
#define PB_SZ 896

extern "C" void kernel_launch(void* const* d_in, const int* in_sizes, int n_in,
                              void* d_out, int out_size, void* d_ws, size_t ws_size,
                              hipStream_t stream) {
    const void* y   = d_in[0];
    const void* ei  = d_in[1];
    const void* ea  = d_in[2];
    const void* W1  = d_in[3];
    const void* b1  = d_in[4];
    const void* g1  = d_in[5];
    const void* be1 = d_in[6];
    const void* W2  = d_in[7];
    const void* b2  = d_in[8];
    const void* g2  = d_in[9];
    const void* be2 = d_in[10];
    const void* W3  = d_in[11];
    const void* g3  = d_in[12];
    const void* be3 = d_in[13];

    char* w = (char*)d_ws;
    size_t used = 0;
    auto carve = [&](size_t bytes) -> char* {
        char* p = w + used;
        used += (bytes + 255) & ~(size_t)255;
        return p;
    };

    int* flags   = (int*)carve(16);
    int* src32   = (int*)carve((size_t)NE * 4);
    int* dst32   = (int*)carve((size_t)NE * 4);
    // deg + cnt adjacent -> single memset
    float* deg   = (float*)carve((size_t)NN * 4 + (size_t)NN * 4);
    int* cnt     = (int*)(deg + NN);
    int* rowptr  = (int*)carve((size_t)(NN + 1) * 4);
    int* cscan   = (int*)carve((size_t)NN * 4);
    int* bsum    = (int*)carve((size_t)SCAN_NB * 4);
    int* csrc    = (int*)carve((size_t)NE * 4);
    float* cw    = (float*)carve((size_t)NE * 4);
    float* PB    = (float*)carve(PB_SZ * 4);
    b16* Wp1     = (b16*)carve((size_t)512 * 128 * 2);
    b16* Wp2     = (b16*)carve((size_t)512 * 128 * 2);
    b16* Wp3     = (b16*)carve((size_t)512 * 64 * 2);
    b16* OUT     = (b16*)carve((size_t)NN * 128 * 2);
    float* GS    = (float*)carve(3 * 256 * 4);  // per-layer gsum[128]|gsq[128]
    b16* XC      = (b16*)carve((size_t)NN * 512 * 2);

    // ----- detection + param normalize + weight pack -----
    k_detect<<<1, 64, 0, stream>>>(y, ei, flags);
    k_cvt_all<<<1, PB_SZ, 0, stream>>>(b1, b2, g1, be1, g2, be2, g3, be3, PB, flags);
    k_pack<<<(512 * 128 / 8 + 255) / 256, 256, 0, stream>>>(W1, Wp1, 128, flags);
    k_pack<<<(512 * 128 / 8 + 255) / 256, 256, 0, stream>>>(W2, Wp2, 128, flags);
    k_pack<<<(512 * 64 / 8 + 255) / 256, 256, 0, stream>>>(W3, Wp3, 64, flags);

    // ----- graph prep -----
    k_idx<<<(NE + 255) / 256, 256, 0, stream>>>(ei, src32, dst32, flags);
    hipMemsetAsync(deg, 0, (size_t)NN * 8, stream);  // deg + cnt
    hipMemsetAsync(GS, 0, 3 * 256 * 4, stream);      // all layer stats
    k_degcnt<<<(NE + 255) / 256, 256, 0, stream>>>(dst32, ea, deg, cnt, flags);
    k_dis<<<(NN + 255) / 256, 256, 0, stream>>>(deg);
    k_scan1<<<SCAN_NB, SCAN_B, 0, stream>>>(cnt, cscan, bsum);
    k_scan2<<<1, 64, 0, stream>>>(bsum);
    k_scan3<<<(NN + 255) / 256, 256, 0, stream>>>(cscan, bsum, rowptr);
    hipMemsetAsync(cnt, 0, (size_t)NN * 4, stream);
    k_fill<<<(NE + 255) / 256, 256, 0, stream>>>(src32, dst32, ea, deg, rowptr, cnt,
                                                 csrc, cw, flags);

    // ----- layers -----
    k_cast<<<(NN * 32 + 255) / 256, 256, 0, stream>>>(y, XC, flags);

    const int spmm_grid = (NN * 64 + 255) / 256;
    const int gemm_grid = (NN + 127) / 128;
    auto spmm = [&](int ci, int co) {
        k_spmm<<<spmm_grid, 256, 0, stream>>>(XC, ci, co, rowptr, csrc, cw);
    };

    // layer 1
    spmm(0, 128);
    spmm(128, 256);
    spmm(256, 384);
    k_mgemm<8><<<gemm_grid, 256, 0, stream>>>(XC, Wp1, PB + PB_B1, OUT, GS + 0,
                                              GS + 128);
    // layer 2 (first hop fused with BN1 apply + X write)
    k_spmm_bn<<<spmm_grid, 256, 0, stream>>>(XC, OUT, 128, rowptr, csrc, cw, GS + 0,
                                             GS + 128, PB + PB_G1, PB + PB_BE1);
    spmm(128, 256);
    spmm(256, 384);
    k_mgemm<8><<<gemm_grid, 256, 0, stream>>>(XC, Wp2, PB + PB_B2, OUT, GS + 256,
                                              GS + 384);
    // layer 3 (first hop fused with BN2 apply + X write)
    k_spmm_bn<<<spmm_grid, 256, 0, stream>>>(XC, OUT, 128, rowptr, csrc, cw, GS + 256,
                                             GS + 384, PB + PB_G2, PB + PB_BE2);
    spmm(128, 256);
    spmm(256, 384);
    k_mgemm<4><<<gemm_grid, 256, 0, stream>>>(XC, Wp3, nullptr, OUT, GS + 512,
                                              GS + 640);
    k_bnlast<<<(NN * 64 + 255) / 256, 256, 0, stream>>>(OUT, GS + 512, GS + 640,
                                                        PB + PB_G3, PB + PB_BE3, d_out,
                                                        flags);
}